// Round 3
// baseline (2979.018 us; speedup 1.0000x reference)
//
#include <hip/hip_runtime.h>
#include <hip/hip_bf16.h>

#define SEQ 2048
#define DM  1024
#define NH  16
#define DK  64
#define QT  16    // q rows per attn_scores block
#define KC  64    // keys per staged chunk
#define OUT_ELEMS ((size_t)2 * SEQ * DM)   // 4194304, element offset of attn in d_out

// ---- dtype-dynamic load/store (flag f: 1 = fp32, 0 = bf16) ----
struct SrcF {
    const float* p; size_t base;
    __device__ float ld(size_t i, int) const { return p[base + i]; }
};
struct SrcDyn {
    const void* p; size_t base;
    __device__ float ld(size_t i, int f) const {
        return f ? ((const float*)p)[base + i]
                 : __bfloat162float(((const __hip_bfloat16*)p)[base + i]);
    }
};
struct DstF {
    float* p; size_t base;
    __device__ void st(size_t i, float v, int) const { p[base + i] = v; }
};
struct DstDyn {
    void* p; size_t base;
    __device__ void st(size_t i, float v, int f) const {
        if (f) ((float*)p)[base + i] = v;
        else   ((__hip_bfloat16*)p)[base + i] = __float2bfloat16(v);
    }
};

// ---- dtype detection: sample 64 words of query, vote on bf16 exponent stats ----
__global__ void detect_dtype(const unsigned int* q, int* flag) {
    unsigned w = q[(size_t)threadIdx.x * 30011 + 7];   // max 1,890,700 < 2M words (safe for bf16 buf)
    int e = (w >> 7) & 0xFF;                           // exponent field of low-half bf16
    int inr = (e >= 115 && e <= 131) ? 1 : 0;          // N(0,1) bf16 lands here w.p. >0.999
    unsigned long long bal = __ballot(inr);
    if (threadIdx.x == 0) *flag = (__popcll(bal) >= 32) ? 0 : 1;  // 0=bf16, 1=fp32
}

// C[M,N] = A[M,K] @ W[K,N] (+ bias). 64x64 tile, BK=32, 4x4 micro-tile, 256 thr.
// z-batched: A/C advance by sAz/sCz per blockIdx.z, W by sWz per (z / wzdiv).
template <class SA, class SW, class SB, class DC>
__global__ __launch_bounds__(256) void gemm_bias(
    SA A, SW W, SB Bv, int hasBias, DC C,
    int M, int N, int K, size_t sAz, size_t sWz, int wzdiv, size_t sCz,
    const int* __restrict__ dflag)
{
    const int f = *dflag;
    const size_t aZ = (size_t)blockIdx.z * sAz;
    const size_t wZ = (size_t)(blockIdx.z / wzdiv) * sWz;
    const size_t cZ = (size_t)blockIdx.z * sCz;

    __shared__ float As[32][68];   // [k][m]
    __shared__ float Bs[32][68];   // [k][n]
    const int tid = threadIdx.x;
    const int tx = tid & 15, ty = tid >> 4;
    const int m0 = blockIdx.y * 64, n0 = blockIdx.x * 64;

    float acc[4][4];
#pragma unroll
    for (int i = 0; i < 4; ++i)
#pragma unroll
        for (int j = 0; j < 4; ++j) acc[i][j] = 0.f;

    for (int k0 = 0; k0 < K; k0 += 32) {
        __syncthreads();
#pragma unroll
        for (int r = 0; r < 8; ++r) {
            int i = tid + 256 * r;            // 0..2047
            int mm = i >> 5, kk = i & 31;     // A tile: 64 m x 32 k
            As[kk][mm] = A.ld(aZ + (size_t)(m0 + mm) * K + (k0 + kk), f);
            int kk2 = i >> 6, nn = i & 63;    // W tile: 32 k x 64 n
            Bs[kk2][nn] = W.ld(wZ + (size_t)(k0 + kk2) * N + (n0 + nn), f);
        }
        __syncthreads();
#pragma unroll
        for (int kk = 0; kk < 32; ++kk) {
            float4 a4 = *(const float4*)&As[kk][ty * 4];
            float4 b4 = *(const float4*)&Bs[kk][tx * 4];
            float a[4] = {a4.x, a4.y, a4.z, a4.w};
            float b[4] = {b4.x, b4.y, b4.z, b4.w};
#pragma unroll
            for (int i = 0; i < 4; ++i)
#pragma unroll
                for (int j = 0; j < 4; ++j) acc[i][j] += a[i] * b[j];
        }
    }

#pragma unroll
    for (int i = 0; i < 4; ++i) {
        int mm = m0 + ty * 4 + i;
#pragma unroll
        for (int j = 0; j < 4; ++j) {
            int nn = n0 + tx * 4 + j;
            float vb = hasBias ? Bv.ld((size_t)nn, f) : 0.f;
            C.st(cZ + (size_t)mm * N + nn, acc[i][j] + vb, f);
        }
    }
}

// scores + softmax + attn write. One block per (b, h, 16 q rows).
// 256 threads; q row owned by 16 lanes (sub), lane sees keys sub+16*jj per chunk.
__global__ __launch_bounds__(256) void attn_scores(
    const float* __restrict__ Qf, const float* __restrict__ Kf,
    DstDyn attn, const int* __restrict__ dflag)
{
    const int f = *dflag;
    __shared__ float Qs[QT][DK];
    __shared__ float Ks[KC][DK + 4];
    __shared__ float redM[QT][17];
    __shared__ float redL[QT][17];

    const int tid = threadIdx.x;
    const int l = tid & 63, w = tid >> 6;
    const int g = l >> 4, sub = l & 15;
    const int qi = w * 4 + g;
    const int q0 = blockIdx.x * QT;
    const int h = blockIdx.y;
    const int b = blockIdx.z;

    const float* Qbase = Qf + (size_t)b * SEQ * DM + (size_t)h * DK;
    const float* Kb = Kf + (size_t)b * SEQ * DK;

    {   // stage Q tile (16 x 64)
        int qq = tid >> 4, dd = (tid & 15) * 4;
        *(float4*)&Qs[qq][dd] = *(const float4*)(Qbase + (size_t)(q0 + qq) * DM + dd);
    }

    // pass 1: per-lane online (m, lsum)
    float m = -3.0e38f, lsum = 0.f;
    for (int c = 0; c < SEQ / KC; ++c) {
        __syncthreads();
#pragma unroll
        for (int r = 0; r < 4; ++r) {
            int i = tid + 256 * r;
            int kk = i >> 4, dd = (i & 15) * 4;
            *(float4*)&Ks[kk][dd] = *(const float4*)(Kb + (size_t)(c * KC + kk) * DK + dd);
        }
        __syncthreads();
        const float4* qrow = (const float4*)&Qs[qi][0];
#pragma unroll
        for (int jj = 0; jj < 4; ++jj) {
            int kloc = sub + 16 * jj;
            const float4* krow = (const float4*)&Ks[kloc][0];
            float ax = 0.f, ay = 0.f, az = 0.f, aw = 0.f;
#pragma unroll
            for (int dd = 0; dd < 16; ++dd) {
                float4 kv = krow[dd], qv = qrow[dd];
                ax += kv.x * qv.x; ay += kv.y * qv.y;
                az += kv.z * qv.z; aw += kv.w * qv.w;
            }
            float s = (ax + ay + az + aw) * 0.125f;
            float mn = fmaxf(m, s);
            lsum = lsum * expf(m - mn) + expf(s - mn);
            m = mn;
        }
    }
    redM[qi][sub] = m;
    redL[qi][sub] = lsum;
    __syncthreads();
    float M = -3.0e38f;
#pragma unroll
    for (int t = 0; t < 16; ++t) M = fmaxf(M, redM[qi][t]);
    float L = 0.f;
#pragma unroll
    for (int t = 0; t < 16; ++t) L += redL[qi][t] * expf(redM[qi][t] - M);
    const float invL = 1.f / L;

    // pass 2: recompute, write normalized probs
    for (int c = 0; c < SEQ / KC; ++c) {
        __syncthreads();
#pragma unroll
        for (int r = 0; r < 4; ++r) {
            int i = tid + 256 * r;
            int kk = i >> 4, dd = (i & 15) * 4;
            *(float4*)&Ks[kk][dd] = *(const float4*)(Kb + (size_t)(c * KC + kk) * DK + dd);
        }
        __syncthreads();
        const float4* qrow = (const float4*)&Qs[qi][0];
#pragma unroll
        for (int jj = 0; jj < 4; ++jj) {
            int kloc = sub + 16 * jj;
            const float4* krow = (const float4*)&Ks[kloc][0];
            float ax = 0.f, ay = 0.f, az = 0.f, aw = 0.f;
#pragma unroll
            for (int dd = 0; dd < 16; ++dd) {
                float4 kv = krow[dd], qv = qrow[dd];
                ax += kv.x * qv.x; ay += kv.y * qv.y;
                az += kv.z * qv.z; aw += kv.w * qv.w;
            }
            float s = (ax + ay + az + aw) * 0.125f;
            float p = expf(s - M) * invL;
            attn.st(((size_t)(b * NH + h) * SEQ + (q0 + qi)) * SEQ + (c * KC + kloc), p, f);
        }
    }
}

extern "C" void kernel_launch(void* const* d_in, const int* in_sizes, int n_in,
                              void* d_out, int out_size, void* d_ws, size_t ws_size,
                              hipStream_t stream) {
    const void* query = d_in[0];
    const void* key   = d_in[1];
    const void* value = d_in[2];
    const void* w_q = d_in[3];
    const void* b_q = d_in[4];
    const void* w_k = d_in[5];
    const void* b_k = d_in[6];
    const void* w_v = d_in[7];
    const void* b_v = d_in[8];
    const void* w_o = d_in[9];
    const void* b_o = d_in[10];

    const size_t M = (size_t)2 * SEQ;   // 4096 rows
    int*   flag = (int*)d_ws;
    float* Qf  = (float*)d_ws + 16;     // [4096,1024]
    float* Kf  = Qf + M * DM;           // [4096,64]
    float* Vf  = Kf + M * DK;           // [4096,64]
    float* AOf = Vf + M * DK;           // heads, FLAT [B,H,S,DK] = [4096,1024]

    // 0) detect input/output element type (writes flag: 1=fp32, 0=bf16)
    detect_dtype<<<1, 64, 0, stream>>>((const unsigned int*)query, flag);

    // 1) projections (fp32 results in ws)
    gemm_bias<<<dim3(16, 64, 1), 256, 0, stream>>>(
        SrcDyn{query, 0}, SrcDyn{w_q, 0}, SrcDyn{b_q, 0}, 1, DstF{Qf, 0},
        (int)M, DM, DM, (size_t)0, (size_t)0, 1, (size_t)0, flag);
    gemm_bias<<<dim3(1, 64, 1), 256, 0, stream>>>(
        SrcDyn{key, 0}, SrcDyn{w_k, 0}, SrcDyn{b_k, 0}, 1, DstF{Kf, 0},
        (int)M, DK, DM, (size_t)0, (size_t)0, 1, (size_t)0, flag);
    gemm_bias<<<dim3(1, 64, 1), 256, 0, stream>>>(
        SrcDyn{value, 0}, SrcDyn{w_v, 0}, SrcDyn{b_v, 0}, 1, DstF{Vf, 0},
        (int)M, DK, DM, (size_t)0, (size_t)0, 1, (size_t)0, flag);

    // 2) softmax(QK^T/8) -> attn region of d_out (element offset OUT_ELEMS)
    attn_scores<<<dim3(SEQ / QT, NH, 2), 256, 0, stream>>>(
        Qf, Kf, DstDyn{d_out, OUT_ELEMS}, flag);

    // 3) heads[bh] = attn[bh] @ V[b]  -> AOf flat [B,H,S,DK]
    gemm_bias<<<dim3(1, SEQ / 64, 2 * NH), 256, 0, stream>>>(
        SrcDyn{d_out, OUT_ELEMS}, SrcF{Vf, 0}, SrcF{Vf, 0}, 0, DstF{AOf, 0},
        SEQ, DK, SEQ, (size_t)SEQ * SEQ, (size_t)SEQ * DK, NH, (size_t)SEQ * DK, flag);

    // 4) out = reshape(heads) @ w_o + b_o -> out region of d_out
    gemm_bias<<<dim3(16, 64, 1), 256, 0, stream>>>(
        SrcF{AOf, 0}, SrcDyn{w_o, 0}, SrcDyn{b_o, 0}, 1, DstDyn{d_out, 0},
        (int)M, DM, DM, (size_t)0, (size_t)0, 1, (size_t)0, flag);
}